// Round 8
// baseline (227.768 us; speedup 1.0000x reference)
//
#include <hip/hip_runtime.h>
#include <math.h>

// Non-explicit FP stays separate mul/add; explicit fma models the reference's
// contraction (XLA CPU AllowFPOpFusion::Fast). NUMERICS FROZEN SINCE R3:
// absmax 1.117587e-08. All transforms since are bit-identical per element:
//  - v_pk_* round each 32-bit lane exactly like scalar (R7 verified).
//  - A2/A4/gram are bitwise symmetric (IEEE sub antisymmetry + exact mul
//    commutation, same k-order) -> compute upper, mirror/weight (R5/R6/R7
//    all verified absmax-stable across these equivalent forms).
//  - fused augmented elimination == getrf+laswp+trsm bitwise (R7 verified);
//    Q entries j<k are dead at step k (their L column was consumed by the
//    same-step P-axpy) -> swapping them is unobservable.
//  - tree argmax with first-max preference == linear isamax scan (associative).
#pragma clang fp contract(off)

typedef float f2 __attribute__((ext_vector_type(2)));

static __device__ __forceinline__ f2 sp(float x) { f2 r; r.x = x; r.y = x; return r; }
static __device__ __forceinline__ f2 mk2(float x, float y) { f2 r; r.x = x; r.y = y; return r; }
#define FMA2(A, B, C) __builtin_elementwise_fma((A), (B), (C))

// element access into row-major f2-packed 8x8: m[i*4 + (j>>1)] lane (j&1)
#define EL(m, i, j) (m[(i)*4 + ((j) >> 1)][(j) & 1])

// Full 8x8 matmul, fmaf k-chain, f2-paired over j (rare squaring path only).
__device__ __forceinline__ void mm8p(const f2* __restrict__ A,
                                     const f2* __restrict__ B,
                                     f2* __restrict__ C) {
  #pragma unroll
  for (int i = 0; i < 8; ++i) {
    #pragma unroll
    for (int c = 0; c < 4; ++c) {
      f2 s = sp(EL(A, i, 0)) * B[0*4 + c];
      #pragma unroll
      for (int k = 1; k < 8; ++k)
        s = FMA2(sp(EL(A, i, k)), B[k*4 + c], s);
      C[i*4 + c] = s;
    }
  }
}

// Symmetric product C = M*M (M bitwise symmetric or skew): compute f2 dots
// only for rows i <= 2c+1 (covers upper+diag), mirror the strict-lower part.
// Each computed entry has the identical full 8-term chain as the full version;
// mirrored entries are bitwise equal by the symmetry proofs.
__device__ __forceinline__ void mm8p_sym(const f2* __restrict__ M,
                                         f2* __restrict__ C) {
  #pragma unroll
  for (int c = 0; c < 4; ++c)
    #pragma unroll
    for (int i = 0; i <= 2*c + 1; ++i) {
      f2 s = sp(EL(M, i, 0)) * M[0*4 + c];
      #pragma unroll
      for (int k = 1; k < 8; ++k)
        s = FMA2(sp(EL(M, i, k)), M[k*4 + c], s);
      C[i*4 + c] = s;
    }
  // mirrors: (i,j) i>j <- (j,i), all sources computed above (row j<=2c'+1)
  #pragma unroll
  for (int c = 0; c < 4; ++c)
    #pragma unroll
    for (int i = 2*c + 2; i < 8; ++i) {
      EL(C, i, 2*c)     = EL(C, 2*c,     i);
      EL(C, i, 2*c + 1) = EL(C, 2*c + 1, i);
    }
}

// One thread per 8x8 block, 256-thread workgroups, NO min-waves bound:
// caps force spill (R4: 677MB, R6: 43MB scratch). R7 natural alloc = 128 VGPR
// = exactly the 4-waves/SIMD boundary, zero spill.
__global__ __launch_bounds__(256, 1)
void triality_kernel(const float* __restrict__ in, double* __restrict__ acc)
{
  const int t = blockIdx.x * 256 + threadIdx.x;
  const float4* src = (const float4*)(in + (size_t)t * 64);

  float p[64];
  #pragma unroll
  for (int i = 0; i < 16; ++i) {
    float4 q4 = src[i];
    p[4*i+0] = q4.x; p[4*i+1] = q4.y; p[4*i+2] = q4.z; p[4*i+3] = q4.w;
  }

  // A = 0.5*(P - P^T) (diag = +0 exactly)
  f2 aa[32];
  #pragma unroll
  for (int i = 0; i < 8; ++i)
    #pragma unroll
    for (int j = 0; j < 8; ++j)
      EL(aa, i, j) = 0.5f * (p[i*8+j] - p[j*8+i]);

  // 1-norm: per column j ascending i (identical op order to validated R5/R7)
  float l1 = 0.0f;
  #pragma unroll
  for (int j = 0; j < 8; ++j) {
    float cs = 0.0f;
    #pragma unroll
    for (int i = 0; i < 8; ++i) cs = cs + fabsf(EL(aa, i, j));
    l1 = fmaxf(l1, cs);
  }

  // n_squarings = max(0, floor(log2(A_L1 / 3.925724783138660)))
  float fl = floorf(log2f(l1 / 3.925724783138660f));
  int ns = (fl > 0.0f) ? (int)fl : 0;
  if (ns > 0) {
    f2 sc = sp(exp2f((float)(-ns)));   // exact power of two
    #pragma unroll
    for (int e = 0; e < 32; ++e) aa[e] = aa[e] * sc;
  }

  // A2 = A*A (skew -> symmetric), A4 = A2*A2 (symmetric): upper + mirror
  f2 a2[32], a4[32];
  mm8p_sym(aa, a2);
  mm8p_sym(a2, a4);

  // A6 = A4*A2: NOT bitwise symmetric -> full
  f2 w6[32];
  #pragma unroll
  for (int i = 0; i < 8; ++i)
    #pragma unroll
    for (int c = 0; c < 4; ++c) {
      f2 s = sp(EL(a4, i, 0)) * a2[0*4 + c];
      #pragma unroll
      for (int k = 1; k < 8; ++k)
        s = FMA2(sp(EL(a4, i, k)), a2[k*4 + c], s);
      w6[i*4 + c] = s;
    }

  // XLA backend-fused polynomial combine (validated R3):
  //   W = fma(277200, A2, fma(1512, A4, A6)) + diag(8648640)   (into w6)
  //   V = fma(1995840, A2, fma(56, A6, 25200*A4)) + diag(17297280)
  f2 vv[32];
  #pragma unroll
  for (int e = 0; e < 32; ++e) {
    f2 x6 = w6[e], x4 = a4[e], x2 = a2[e];
    f2 w = FMA2(sp(1512.0f), x4, x6);
    w = FMA2(sp(277200.0f), x2, w);
    f2 v = FMA2(sp(56.0f), x6, sp(25200.0f) * x4);
    v = FMA2(sp(1995840.0f), x2, v);
    w6[e] = w; vv[e] = v;
  }
  #pragma unroll
  for (int i = 0; i < 8; ++i) {   // diagonal adds (scalar halves)
    EL(w6, i, i) = EL(w6, i, i) + 8648640.0f;
    EL(vv, i, i) = EL(vv, i, i) + 17297280.0f;
  }

  // U = A @ W (full chains; k==i term is fmaf(+-0,y,s)==s)
  f2 uu[32];
  #pragma unroll
  for (int i = 0; i < 8; ++i)
    #pragma unroll
    for (int c = 0; c < 4; ++c) {
      f2 s = sp(EL(aa, i, 0)) * w6[0*4 + c];
      #pragma unroll
      for (int k = 1; k < 8; ++k)
        s = FMA2(sp(EL(aa, i, k)), w6[k*4 + c], s);
      uu[i*4 + c] = s;
    }

  // P = U + V (into uu), Q = V - U (into vv)
  #pragma unroll
  for (int e = 0; e < 32; ++e) {
    f2 U = uu[e], V = vv[e];
    uu[e] = U + V;
    vv[e] = V - U;
  }
  f2* P = uu;
  f2* Q = vv;

  // ---- fused augmented elimination on [Q|P] (bit-identical, R7-validated) --
  #pragma unroll
  for (int k = 0; k < 8; ++k) {
    // tree argmax over rows k..7, first-max preference (== linear isamax)
    float bv[8]; int bi[8]; int n = 8 - k;
    #pragma unroll
    for (int i = 0; i < 8; ++i) {
      if (i < 8 - k) { bv[i] = fabsf(EL(Q, k + i, k)); bi[i] = k + i; }
    }
    #pragma unroll
    for (int stride = 1; stride < 8; stride <<= 1) {
      #pragma unroll
      for (int i = 0; i + stride < 8; i += 2 * stride) {
        if (i + stride < n) {
          bool g = bv[i + stride] > bv[i];     // strict: keep left on ties
          bv[i] = g ? bv[i + stride] : bv[i];
          bi[i] = g ? bi[i + stride] : bi[i];
        }
      }
    }
    int jp = bi[0];
    // swap rows k<->jp: Q only j>=k (j<k entries are dead), P full width
    #pragma unroll
    for (int i = k + 1; i < 8; ++i) {
      bool d = (jp == i);
      #pragma unroll
      for (int j = k; j < 8; ++j) {
        float x = EL(Q, k, j), y = EL(Q, i, j);
        EL(Q, k, j) = d ? y : x;
        EL(Q, i, j) = d ? x : y;
      }
      #pragma unroll
      for (int c = 0; c < 4; ++c) {
        f2 px = P[k*4 + c], py = P[i*4 + c];
        P[k*4 + c] = d ? py : px;
        P[i*4 + c] = d ? px : py;
      }
    }
    // pivot-column scale: direct IEEE divide (validated R3)
    float dk = EL(Q, k, k);
    #pragma unroll
    for (int i = k + 1; i < 8; ++i) EL(Q, i, k) = EL(Q, i, k) / dk;
    // trailing updates: Q rank-1 (scalar) + P row-axpy (pk)
    #pragma unroll
    for (int i = k + 1; i < 8; ++i) {
      float lik = EL(Q, i, k);
      #pragma unroll
      for (int j = k + 1; j < 8; ++j)
        EL(Q, i, j) = __builtin_fmaf(-lik, EL(Q, k, j), EL(Q, i, j));
      f2 nl = sp(-lik);
      #pragma unroll
      for (int c = 0; c < 4; ++c)
        P[i*4 + c] = FMA2(nl, P[k*4 + c], P[i*4 + c]);
    }
  }

  // strsm: non-unit upper, k descending, IEEE f32 divide per element
  #pragma unroll
  for (int k = 7; k >= 0; --k) {
    float dk = EL(Q, k, k);
    #pragma unroll
    for (int j = 0; j < 8; ++j) EL(P, k, j) = EL(P, k, j) / dk;
    #pragma unroll
    for (int i = 0; i < k; ++i) {
      f2 nu = sp(-EL(Q, i, k));
      #pragma unroll
      for (int c = 0; c < 4; ++c)
        P[i*4 + c] = FMA2(nu, P[k*4 + c], P[i*4 + c]);
    }
  }

  // repeated squaring (ns in {0,1} statistically)
  for (int sq = 0; sq < ns; ++sq) {
    f2 t2[32];
    mm8p(P, P, t2);
    #pragma unroll
    for (int e = 0; e < 32; ++e) P[e] = t2[e];
  }

  // gram = R^T R - I: bitwise symmetric -> upper f2 dots with weight
  // vectors {0,1,2} (0 kills the duplicated lower lane; fma(0,e2,s)==s).
  // Chain per computed entry identical to validated scalar form.
  f2 s2p = sp(0.0f);
  #pragma unroll
  for (int c = 0; c < 4; ++c) {
    #pragma unroll
    for (int i = 0; i <= 2*c + 1; ++i) {
      f2 g = sp(EL(P, 0, i)) * P[0*4 + c];
      #pragma unroll
      for (int j = 1; j < 8; ++j)
        g = FMA2(sp(EL(P, j, i)), P[j*4 + c], g);
      f2 idv = mk2((i == 2*c) ? 1.0f : 0.0f, (i == 2*c + 1) ? 1.0f : 0.0f);
      f2 e = g - idv;
      f2 wv = mk2((i < 2*c) ? 2.0f : (i == 2*c) ? 1.0f : 0.0f,
                  (i < 2*c + 1) ? 2.0f : 1.0f);
      s2p = FMA2(wv, e * e, s2p);
    }
  }
  float frob = sqrtf(s2p.x + s2p.y);

  // wave shuffle reduce (f64) -> LDS -> one atomic per 256-thread block
  double dv = (double)frob;
  #pragma unroll
  for (int off = 32; off > 0; off >>= 1)
    dv += __shfl_down(dv, off);

  __shared__ double part[4];
  const int lane = threadIdx.x & 63;
  const int wid  = threadIdx.x >> 6;
  if (lane == 0) part[wid] = dv;
  __syncthreads();
  if (threadIdx.x == 0) {
    double s = (part[0] + part[1]) + (part[2] + part[3]);
    atomicAdd(acc, s);
  }
}

__global__ void finalize_kernel(const double* __restrict__ acc,
                                float* __restrict__ out, int nmat)
{
  out[0] = (float)(acc[0] / (double)nmat);
}

extern "C" void kernel_launch(void* const* d_in, const int* in_sizes, int n_in,
                              void* d_out, int out_size, void* d_ws, size_t ws_size,
                              hipStream_t stream) {
  const float* in = (const float*)d_in[0];
  float* out = (float*)d_out;
  double* acc = (double*)d_ws;
  int nmat = in_sizes[0] / 64;   // 524288
  hipMemsetAsync(d_ws, 0, sizeof(double), stream);
  triality_kernel<<<nmat / 256, 256, 0, stream>>>(in, acc);
  finalize_kernel<<<1, 1, 0, stream>>>(acc, out, nmat);
}